// Round 3
// baseline (732.184 us; speedup 1.0000x reference)
//
#include <hip/hip_runtime.h>
#include <math.h>

#define T_TOKENS 32768
#define DIM 2048
#define N_EXPERTS 256
#define N_GROUPS 8
#define EPG 32
#define TOPK 8
#define TOPK_GROUPS 4
#define ROUTE_SCALE 2.5f

#define BM 64           // tokens per block; grid 512 -> 2 blocks/CU
#define BK 32           // K-chunk per iteration
#define KITERS (DIM / BK)
#define W_SCALE 256.0f  // pre-scale W so w_lo stays normal in fp16
#define INV_W_SCALE (1.0f / 256.0f)

typedef unsigned short u16;
typedef _Float16 f16x8 __attribute__((ext_vector_type(8)));
typedef float f32x4 __attribute__((ext_vector_type(4)));

__device__ __forceinline__ u16 f16_bits(_Float16 h) {
    union { _Float16 f; u16 u; } c; c.f = h; return c.u;
}

// ---------------------------------------------------------------------------
// Kernel 1: split 256*W (fp32) into fp16 hi/lo planes. 2 MB, L2-resident.
// ---------------------------------------------------------------------------
__global__ __launch_bounds__(256) void convert_w(
    const float* __restrict__ W, u16* __restrict__ Whi, u16* __restrict__ Wlo)
{
    const int i = blockIdx.x * 256 + threadIdx.x;   // 524288 total
    const float x = W[i] * W_SCALE;
    const _Float16 hi = (_Float16)x;
    const _Float16 lo = (_Float16)(x - (float)hi);
    Whi[i] = f16_bits(hi);
    Wlo[i] = f16_bits(lo);
}

// split 8 fp32 (two float4) into fp16 hi/lo fragments — identical arithmetic
// to the LDS-staged version (bit-exact logits vs R1 kernel).
__device__ __forceinline__ void split8(const float4 p, const float4 q,
                                       f16x8* hi, f16x8* lo)
{
    const float v[8] = {p.x, p.y, p.z, p.w, q.x, q.y, q.z, q.w};
    #pragma unroll
    for (int k = 0; k < 8; k++) {
        const _Float16 h = (_Float16)v[k];
        (*hi)[k] = h;
        (*lo)[k] = (_Float16)(v[k] - (float)h);
    }
}

// ---------------------------------------------------------------------------
// Kernel 2: fused  sigmoid(X @ W^T) + bias  ->  group-limited top-k routing.
// BARRIER-FREE K-loop: MFMA fragments are k-contiguous 8-element runs, so A
// and B load straight from global (X coalesced 128B/row-group from HBM; W
// planes L2-resident) — no LDS staging, no per-iter syncthreads, no convoy.
// 8 waves (2m x 4n), each 32 tokens x 64 experts. LDS = score buffer only.
// Split-fp16 3-term MFMA (hh + hl + lh): bit-identical numerics to R1.
// ---------------------------------------------------------------------------
__global__ __launch_bounds__(512, 4) void fused_gate(
    const float* __restrict__ X,
    const u16* __restrict__ Whi, const u16* __restrict__ Wlo,
    const float* __restrict__ bias,
    float* __restrict__ out_w, float* __restrict__ out_i)
{
    __shared__ float Sc[BM * N_EXPERTS];   // 64 KB: biased scores

    const int tid = threadIdx.x;
    const int m0 = blockIdx.x * BM;

    const int lane = tid & 63;
    const int wave = tid >> 6;
    const int wm = wave >> 2;         // 0..1: token half (32 rows)
    const int wn = wave & 3;          // 0..3: expert quarter (64 experts)
    const int l16 = lane & 15;
    const int quad = lane >> 4;

    // A: lane reads 8 fp32 of row (m0 + wm*32 + i*16 + l16) at k = it*32 + quad*8
    const float* xa0 = X + (size_t)(m0 + wm * 32 + l16) * DIM + quad * 8;
    const float* xa1 = xa0 + 16 * DIM;
    // B: lane reads 8 u16 of W-row (wn*64 + j*16 + l16) at same k
    const u16* wbh = Whi + (size_t)(wn * 64 + l16) * DIM + quad * 8;
    const u16* wbl = Wlo + (size_t)(wn * 64 + l16) * DIM + quad * 8;

    f32x4 acc[2][4];
    #pragma unroll
    for (int i = 0; i < 2; i++)
        #pragma unroll
        for (int j = 0; j < 4; j++) acc[i][j] = (f32x4){0.f, 0.f, 0.f, 0.f};

    // prefetch A chunk for it=0
    float4 a00 = *(const float4*)(xa0);
    float4 a01 = *(const float4*)(xa0 + 4);
    float4 a10 = *(const float4*)(xa1);
    float4 a11 = *(const float4*)(xa1 + 4);

    #pragma unroll 2
    for (int it = 0; it < KITERS; ++it) {
        const int cur = it * BK;

        // --- B fragments for this iter: 8 x 16B from L2-resident W planes ---
        f16x8 fbh[4], fbl[4];
        #pragma unroll
        for (int j = 0; j < 4; j++) {
            fbh[j] = *(const f16x8*)(wbh + (size_t)j * 16 * DIM + cur);
            fbl[j] = *(const f16x8*)(wbl + (size_t)j * 16 * DIM + cur);
        }

        // --- prefetch next A chunk (HBM latency hides under convert+MFMA) ---
        float4 n00, n01, n10, n11;
        if (it + 1 < KITERS) {
            const int nxt = cur + BK;
            n00 = *(const float4*)(xa0 + nxt);
            n01 = *(const float4*)(xa0 + nxt + 4);
            n10 = *(const float4*)(xa1 + nxt);
            n11 = *(const float4*)(xa1 + nxt + 4);
        }

        // --- in-register A split (same arithmetic as staged version) ---
        f16x8 fah[2], fal[2];
        split8(a00, a01, &fah[0], &fal[0]);
        split8(a10, a11, &fah[1], &fal[1]);

        // --- 3-term split-fp16 MFMA: hh + hl + lh (ll term is O(2^-24)) ---
        #pragma unroll
        for (int i = 0; i < 2; i++)
            #pragma unroll
            for (int j = 0; j < 4; j++) {
                acc[i][j] = __builtin_amdgcn_mfma_f32_16x16x32_f16(fah[i], fbh[j], acc[i][j], 0, 0, 0);
                acc[i][j] = __builtin_amdgcn_mfma_f32_16x16x32_f16(fah[i], fbl[j], acc[i][j], 0, 0, 0);
                acc[i][j] = __builtin_amdgcn_mfma_f32_16x16x32_f16(fal[i], fbh[j], acc[i][j], 0, 0, 0);
            }

        if (it + 1 < KITERS) { a00 = n00; a01 = n01; a10 = n10; a11 = n11; }
    }

    // --- epilogue: biased sigmoid scores -> LDS, then fused routing ---
    float bv[4];
    #pragma unroll
    for (int j = 0; j < 4; j++) bv[j] = bias[wn * 64 + j * 16 + l16];

    #pragma unroll
    for (int i = 0; i < 2; i++)
        #pragma unroll
        for (int j = 0; j < 4; j++)
            #pragma unroll
            for (int r = 0; r < 4; r++) {
                const int trow = wm * 32 + i * 16 + quad * 4 + r;    // 0..63
                const int e = wn * 64 + j * 16 + l16;                // 0..255
                const float logit = acc[i][j][r] * INV_W_SCALE;
                const float s = 1.f / (1.f + expf(-logit));
                Sc[trow * N_EXPERTS + e] = s + bv[j];                // BIASED
            }
    __syncthreads();   // all waves' scores visible to the routing wave

    if (tid < 64) {    // one wave routes 64 tokens; lane-staggered LDS reads
        const float* row = Sc + tid * N_EXPERTS;

        // group score = sum of top-2 biased (matches jax order: m1+m2)
        float gs[N_GROUPS];
        #pragma unroll
        for (int g = 0; g < N_GROUPS; g++) {
            float m1 = -INFINITY, m2 = -INFINITY;
            #pragma unroll
            for (int jj = 0; jj < EPG; jj++) {
                const float v = row[g * EPG + ((tid + jj) & (EPG - 1))];
                if (v > m1) { m2 = m1; m1 = v; }
                else if (v > m2) { m2 = v; }
            }
            gs[g] = m1 + m2;
        }
        // keep top-4 groups (jax tie-break: lower index wins)
        unsigned keep = 0;
        #pragma unroll
        for (int g = 0; g < N_GROUPS; g++) {
            int cnt = 0;
            #pragma unroll
            for (int h = 0; h < N_GROUPS; h++)
                if (gs[h] > gs[g] || (gs[h] == gs[g] && h < g)) cnt++;
            if (cnt < TOPK_GROUPS) keep |= (1u << g);
        }
        // top-8 experts within kept groups; comparator (v desc, idx asc)
        // makes result independent of staggered scan order
        float tv[TOPK]; int ti[TOPK];
        #pragma unroll
        for (int i = 0; i < TOPK; i++) { tv[i] = -INFINITY; ti[i] = 0x7fffffff; }
        for (int g = 0; g < N_GROUPS; g++) {
            if (!(keep & (1u << g))) continue;
            #pragma unroll 4
            for (int jj = 0; jj < EPG; jj++) {
                const int e = g * EPG + ((tid + jj) & (EPG - 1));
                const float v = row[e];
                if (v > tv[TOPK - 1] || (v == tv[TOPK - 1] && e < ti[TOPK - 1])) {
                    float cv = v; int ce = e;
                    #pragma unroll
                    for (int s = 0; s < TOPK; s++) {
                        const bool b = (cv > tv[s]) || (cv == tv[s] && ce < ti[s]);
                        if (b) {
                            const float t1 = tv[s]; tv[s] = cv; cv = t1;
                            const int t2 = ti[s]; ti[s] = ce; ce = t2;
                        }
                    }
                }
            }
        }
        // weights from RAW scores (biased - bias), normalize, scale
        float w[TOPK], sum = 0.f;
        #pragma unroll
        for (int i = 0; i < TOPK; i++) {
            w[i] = row[ti[i]] - bias[ti[i]];
            sum += w[i];
        }
        const float scale = ROUTE_SCALE / fmaxf(sum, 1e-10f);
        const size_t t = (size_t)m0 + tid;
        #pragma unroll
        for (int i = 0; i < TOPK; i++) {
            out_w[t * TOPK + i] = w[i] * scale;
            out_i[t * TOPK + i] = (float)ti[i];
        }
    }
}

extern "C" void kernel_launch(void* const* d_in, const int* in_sizes, int n_in,
                              void* d_out, int out_size, void* d_ws, size_t ws_size,
                              hipStream_t stream)
{
    const float* x = (const float*)d_in[0];     // (T, D)
    const float* w = (const float*)d_in[1];     // (E, D)
    const float* b = (const float*)d_in[2];     // (E,)

    u16* whi = (u16*)d_ws;                      // (E, D) fp16 hi plane, 1 MB
    u16* wlo = whi + (size_t)N_EXPERTS * DIM;   // (E, D) fp16 lo plane, 1 MB

    float* out_w = (float*)d_out;                              // (T, 8)
    float* out_i = (float*)d_out + (size_t)T_TOKENS * TOPK;    // (T, 8) as fp32

    convert_w<<<(N_EXPERTS * DIM) / 256, 256, 0, stream>>>(w, whi, wlo);
    fused_gate<<<T_TOKENS / BM, 512, 0, stream>>>(x, whi, wlo, b, out_w, out_i);
}